// Round 19
// baseline (59.124 us; speedup 1.0000x reference)
//
#include <hip/hip_runtime.h>
#include <hip/hip_fp16.h>

#define IMG 128
#define NPIX (IMG * IMG)
#define NT 64
#define LSU 129          // u32 row stride of Z staging (129 % 32 == 1)
#define ZN (64 * LSU)    // u32s per Z buffer

// thr = round_half_even(linspace(2, 90, 64))
__device__ __constant__ int c_thr[NT] = {
    2, 3, 5, 6, 8, 9, 10, 12, 13, 15, 16, 17, 19, 20, 22, 23,
    24, 26, 27, 29, 30, 31, 33, 34, 36, 37, 38, 40, 41, 43, 44, 45,
    47, 48, 49, 51, 52, 54, 55, 56, 58, 59, 61, 62, 63, 65, 66, 68,
    69, 70, 72, 73, 75, 76, 77, 79, 80, 82, 83, 84, 86, 87, 89, 90};

__device__ __forceinline__ int rev7(int x) { return (int)(__brev((unsigned)x) >> 25); }

__device__ __forceinline__ unsigned packh2(float x, float y) {
    __half2 h = __floats2half2_rn(x, y);
    return *reinterpret_cast<unsigned*>(&h);
}
__device__ __forceinline__ float2 unpackh2(unsigned u) {
    __half2 h;
    *reinterpret_cast<unsigned*>(&h) = u;
    return __half22float2(h);
}

// cross-lane pulls -- ALL on the VALU pipe (DPP), zero DS ops in the FFT
__device__ __forceinline__ float x1f(float v) {  // lane^1: quad_perm [1,0,3,2]
    return __int_as_float(__builtin_amdgcn_mov_dpp(__float_as_int(v), 0xB1, 0xF, 0xF, true));
}
__device__ __forceinline__ float x2f(float v) {  // lane^2: quad_perm [2,3,0,1]
    return __int_as_float(__builtin_amdgcn_mov_dpp(__float_as_int(v), 0x4E, 0xF, 0xF, true));
}
__device__ __forceinline__ float x3f(float v) {  // lane^3: quad_perm [3,2,1,0]
    return __int_as_float(__builtin_amdgcn_mov_dpp(__float_as_int(v), 0x1B, 0xF, 0xF, true));
}
__device__ __forceinline__ float x7f(float v) {  // lane^7: row_half_mirror
    return __int_as_float(__builtin_amdgcn_mov_dpp(__float_as_int(v), 0x141, 0xF, 0xF, true));
}
__device__ __forceinline__ float x4f(float v) { return x7f(x3f(v)); }  // lane^4
__device__ __forceinline__ float x8f(float v) {  // lane^8: row_ror:8
    return __int_as_float(__builtin_amdgcn_mov_dpp(__float_as_int(v), 0x128, 0xF, 0xF, true));
}

// ---- macro bodies: no function boundaries -> guaranteed SROA to registers ----
// (rounds 10/11/15 lesson: only these exact bodies proven spill-free. Round 16
// lesson: buf must hold RAW loads -- subtract-at-load forces an early vmcnt
// drain and kills the prefetch-under-compute)

#define BFLY(ar, ai, br, bi, wc, wsn)    \
    do {                                 \
        const float dr_ = (ar) - (br);   \
        const float di_ = (ai) - (bi);   \
        (ar) += (br);                    \
        (ai) += (bi);                    \
        (br) = dr_ * (wc)-di_ * (wsn);   \
        (bi) = dr_ * (wsn) + di_ * (wc); \
    } while (0)

#define XSTAGE(vr, vi, XF, cc, ss, sg)                    \
    do {                                                  \
        _Pragma("unroll") for (int j = 0; j < 8; ++j) {   \
            const float pr_ = XF(vr[j]), pi_ = XF(vi[j]); \
            const float xr_ = fmaf((sg), vr[j], pr_);     \
            const float xi_ = fmaf((sg), vi[j], pi_);     \
            vr[j] = xr_ * (cc)-xi_ * (ss);                \
            vi[j] = xr_ * (ss) + xi_ * (cc);              \
        }                                                 \
    } while (0)

#define FFT128(vr, vi)                                                \
    do {                                                              \
        _Pragma("unroll") for (int j = 0; j < 4; ++j)                 \
            BFLY(vr[j], vi[j], vr[j + 4], vi[j + 4], c64[j], s64[j]); \
        BFLY(vr[0], vi[0], vr[2], vi[2], c32[0], s32[0]);             \
        BFLY(vr[1], vi[1], vr[3], vi[3], c32[1], s32[1]);             \
        BFLY(vr[4], vi[4], vr[6], vi[6], c32[0], s32[0]);             \
        BFLY(vr[5], vi[5], vr[7], vi[7], c32[1], s32[1]);             \
        _Pragma("unroll") for (int j = 0; j < 8; j += 2)              \
            BFLY(vr[j], vi[j], vr[j + 1], vi[j + 1], c16v, s16v);     \
        XSTAGE(vr, vi, x8f, c8v, s8v, sg8);                           \
        XSTAGE(vr, vi, x4f, c4v, s4v, sg4);                           \
        XSTAGE(vr, vi, x2f, c2v, s2v, sg2);                           \
        _Pragma("unroll") for (int j = 0; j < 8; ++j) {               \
            const float pr_ = x1f(vr[j]), pi_ = x1f(vi[j]);           \
            vr[j] = fmaf(sg1, vr[j], pr_);                            \
            vi[j] = fmaf(sg1, vi[j], pi_);                            \
        }                                                             \
    } while (0)

// RAW loads only -- waitcnt defers to STROW, so these fly under the col pass
#define LDROW(ch, buf)                                                                  \
    do {                                                                                \
        const float* pe_ = pred + ibase + (size_t)(ch)*NPIX + (size_t)(2 * rrow) * IMG; \
        const float* ge_ = gt + ibase + (size_t)(ch)*NPIX + (size_t)(2 * rrow) * IMG;   \
        _Pragma("unroll") for (int j = 0; j < 8; ++j) {                                 \
            const int o_ = 16 * j + l;                                                  \
            buf[j] = pe_[o_];                                                           \
            buf[8 + j] = pe_[IMG + o_];                                                 \
            buf[16 + j] = ge_[o_];                                                      \
            buf[24 + j] = ge_[IMG + o_];                                                \
        }                                                                               \
    } while (0)

#define STROW(buf, zb)                                            \
    do {                                                          \
        _Pragma("unroll") for (int j = 0; j < 8; ++j) {           \
            vr[j] = 0.5f * (buf[j] - buf[16 + j]);                \
            vi[j] = 0.5f * (buf[8 + j] - buf[24 + j]);            \
        }                                                         \
        FFT128(vr, vi);                                           \
        _Pragma("unroll") for (int j = 0; j < 8; ++j)             \
            (zb)[rrow * LSU + 16 * j + l] = packh2(vr[j], vi[j]); \
    } while (0)

#define COLONE(u, wf, zb)                                          \
    do {                                                           \
        const int c1_ = rev7(u);                                   \
        const int c2_ = rev7((128 - (u)) & 127);                   \
        _Pragma("unroll") for (int j = 0; j < 8; ++j) {            \
            const int rowo_ = (8 * j + zr) * LSU;                  \
            const float2 A_ = unpackh2((zb)[rowo_ + c1_]);         \
            const float2 B_ = unpackh2((zb)[rowo_ + c2_]);         \
            vr[j] = odd ? (A_.y + B_.y) : (A_.x + B_.x);           \
            vi[j] = odd ? (B_.x - A_.x) : (A_.y - B_.y);           \
        }                                                          \
        FFT128(vr, vi);                                            \
        const float u2f_ = (float)((u) * (u));                     \
        _Pragma("unroll") for (int j = 0; j < 8; ++j) {            \
            const float r2f_ = dy2f[j] + u2f_;                     \
            if ((wf) != 0.0f && r2f_ <= 8100.0f) {                 \
                const int rc_ = (int)ceilf(sqrtf(r2f_) - 3e-4f);   \
                atomicAdd(&s_h[wave][s_rc2bin[rc_]],               \
                          (wf) * (vr[j] * vr[j] + vi[j] * vi[j])); \
            }                                                      \
        }                                                          \
    } while (0)

#define COLPHASE(ch, zb)                                              \
    do {                                                              \
        COLONE(u0, (u0 == 0) ? 1.0f : 2.0f, zb);                      \
        if (wave == (ch)) { COLONE(64, (g == 0) ? 1.0f : 0.0f, zb); } \
    } while (0)

// One block (16 waves) per batch element, channel-pipelined: channel k+1's
// global loads fly under channel k's column pass. Each 16-lane group owns one
// 128-pt FFT (8 complex/lane, slots 16j+l); stages m=64/32/16 lane-local,
// m=8/4/2/1 via DPP. Row-pair Hermitian packing; fp16x2 Z double-buffer.
__global__ __launch_bounds__(1024, 4) void fused_psnr_kernel(const float* __restrict__ pred,
                                                             const float* __restrict__ gt,
                                                             float* __restrict__ out) {
    __shared__ unsigned s_z[2][ZN];  // 2 x 33 KiB fp16x2 Z double-buffer
    __shared__ float s_h[16][66];    // per-wave hist, padded stride
    __shared__ int s_rc2bin[91];

    const int tid = threadIdx.x;
    const int lane = tid & 63;
    const int wave = tid >> 6;  // 0..15
    const int l = lane & 15;    // position within 16-lane FFT group
    const int g = lane >> 4;    // group 0..3 within wave
    const int b = blockIdx.x;

    for (int i = tid; i < 16 * 66; i += 1024) (&s_h[0][0])[i] = 0.0f;
    if (tid < 91) {
        int t = 0;
        while (t < 63 && c_thr[t] < tid) ++t;  // smallest t with thr[t] >= radius
        s_rc2bin[tid] = t;
    }

    // ---- register-resident twiddles via HARDWARE trig (v_sin/v_cos; |arg|<2pi,
    // abs err ~5e-7 << fp16 staging noise; the 13 sincosf lib calls were ~25%
    // of per-thread VALU work at 256 blocks) ----
    const float K = -6.2831853071795864769f * (1.0f / 128.0f);
    float c64[4], s64[4], c32[2], s32[2], c16v, s16v;
#pragma unroll
    for (int j = 0; j < 4; ++j) {
        const float a = K * (float)(16 * j + l);
        s64[j] = __sinf(a);
        c64[j] = __cosf(a);
    }
    {
        const float a0 = K * (float)(2 * l), a1 = K * (float)(2 * l + 32);
        s32[0] = __sinf(a0); c32[0] = __cosf(a0);
        s32[1] = __sinf(a1); c32[1] = __cosf(a1);
        const float a2 = K * (float)(4 * l);
        s16v = __sinf(a2); c16v = __cosf(a2);
    }
    float c8v, s8v, c4v, s4v, c2v, s2v;
    {
        const float a8 = K * (float)((l & 8) ? (l & 7) * 8 : 0);
        const float a4 = K * (float)((l & 4) ? (l & 3) * 16 : 0);
        const float a2 = K * (float)((l & 2) ? (l & 1) * 32 : 0);
        s8v = __sinf(a8); c8v = __cosf(a8);
        s4v = __sinf(a4); c4v = __cosf(a4);
        s2v = __sinf(a2); c2v = __cosf(a2);
    }
    const float sg8 = (l & 8) ? -1.0f : 1.0f;
    const float sg4 = (l & 4) ? -1.0f : 1.0f;
    const float sg2 = (l & 2) ? -1.0f : 1.0f;
    const float sg1 = (l & 1) ? -1.0f : 1.0f;

    const size_t ibase = (size_t)b * 3 * NPIX;
    const int rrow = (wave & 7) + 32 * (wave >> 3) + 8 * g;  // 0..63, unique per unit
    const int u0 = (wave & 3) + ((wave >> 2) << 4) + 4 * g;  // 0..63, unique per unit
    const int zr = l >> 1;
    const int odd = l & 1;

    // per-(lane,j) row-frequency distance^2: slot p=16j+l holds freq rev7(p)
    float dy2f[8];
    const int r4 = ((l & 1) << 3) | ((l & 2) << 1) | ((l & 4) >> 1) | ((l & 8) >> 3);
#pragma unroll
    for (int j = 0; j < 8; ++j) {
        const int fy = (((j & 1) << 2) | (j & 2) | ((j & 4) >> 2)) | (r4 << 3);
        const int dy = (fy < 64) ? fy : 128 - fy;
        dy2f[j] = (float)(dy * dy);
    }

    float bufA[32], bufB[32], vr[8], vi[8];

    // ---- channel pipeline ----
    LDROW(0, bufA);
    STROW(bufA, s_z[0]);
    __syncthreads();  // z0 ready (also covers s_h/rc2bin init)

    LDROW(1, bufB);   // ch1 loads fly under ch0 col pass
    COLPHASE(0, s_z[0]);
    STROW(bufB, s_z[1]);
    __syncthreads();  // z1 ready; z0 readers done

    LDROW(2, bufA);   // ch2 loads fly under ch1 col pass
    COLPHASE(1, s_z[1]);
    STROW(bufA, s_z[0]);
    __syncthreads();  // z0 ready; z1 readers done

    COLPHASE(2, s_z[0]);
    __syncthreads();  // all hist contributions visible

    // ---- combine 16 wave-hists, inclusive prefix, PSNR (wave 0 only) ----
    if (tid < 64) {
        float tot = 0.0f;
#pragma unroll
        for (int w = 0; w < 16; ++w) tot += s_h[w][tid];
        s_h[0][tid] = tot;
        float cum = 0.0f;
        for (int j = 0; j <= tid; ++j) cum += s_h[0][j];
        out[b * NT + tid] = 84.2883987849f - 10.0f * log10f(cum);  // 20*log10(16384) - 10*log10(cum)
    }
}

extern "C" void kernel_launch(void* const* d_in, const int* in_sizes, int n_in,
                              void* d_out, int out_size, void* d_ws, size_t ws_size,
                              hipStream_t stream) {
    const float* pred = (const float*)d_in[0];
    const float* gt = (const float*)d_in[1];
    float* out = (float*)d_out;
    fused_psnr_kernel<<<256, 1024, 0, stream>>>(pred, gt, out);
}

// Round 20
// 53.635 us; speedup vs baseline: 1.1023x; 1.1023x over previous
//
#include <hip/hip_runtime.h>
#include <hip/hip_fp16.h>

#define IMG 128
#define NPIX (IMG * IMG)
#define NT 64
#define LSU 129          // u32 row stride of Z staging (129 % 32 == 1)
#define ZN (64 * LSU)    // u32s per Z buffer

// thr = round_half_even(linspace(2, 90, 64))
__device__ __constant__ int c_thr[NT] = {
    2, 3, 5, 6, 8, 9, 10, 12, 13, 15, 16, 17, 19, 20, 22, 23,
    24, 26, 27, 29, 30, 31, 33, 34, 36, 37, 38, 40, 41, 43, 44, 45,
    47, 48, 49, 51, 52, 54, 55, 56, 58, 59, 61, 62, 63, 65, 66, 68,
    69, 70, 72, 73, 75, 76, 77, 79, 80, 82, 83, 84, 86, 87, 89, 90};

__device__ __forceinline__ int rev7(int x) { return (int)(__brev((unsigned)x) >> 25); }

__device__ __forceinline__ unsigned packh2(float x, float y) {
    __half2 h = __floats2half2_rn(x, y);
    return *reinterpret_cast<unsigned*>(&h);
}
__device__ __forceinline__ float2 unpackh2(unsigned u) {
    __half2 h;
    *reinterpret_cast<unsigned*>(&h) = u;
    return __half22float2(h);
}

// cross-lane pulls -- ALL on the VALU pipe (DPP), zero DS ops in the FFT
__device__ __forceinline__ float x1f(float v) {  // lane^1: quad_perm [1,0,3,2]
    return __int_as_float(__builtin_amdgcn_mov_dpp(__float_as_int(v), 0xB1, 0xF, 0xF, true));
}
__device__ __forceinline__ float x2f(float v) {  // lane^2: quad_perm [2,3,0,1]
    return __int_as_float(__builtin_amdgcn_mov_dpp(__float_as_int(v), 0x4E, 0xF, 0xF, true));
}
__device__ __forceinline__ float x3f(float v) {  // lane^3: quad_perm [3,2,1,0]
    return __int_as_float(__builtin_amdgcn_mov_dpp(__float_as_int(v), 0x1B, 0xF, 0xF, true));
}
__device__ __forceinline__ float x7f(float v) {  // lane^7: row_half_mirror
    return __int_as_float(__builtin_amdgcn_mov_dpp(__float_as_int(v), 0x141, 0xF, 0xF, true));
}
__device__ __forceinline__ float x4f(float v) { return x7f(x3f(v)); }  // lane^4
__device__ __forceinline__ float x8f(float v) {  // lane^8: row_ror:8
    return __int_as_float(__builtin_amdgcn_mov_dpp(__float_as_int(v), 0x128, 0xF, 0xF, true));
}

// ---- macro bodies: no function boundaries -> guaranteed SROA to registers ----
// (rounds 10/11/15: only these exact bodies proven spill-free. Round 16: buf
// must hold RAW loads -- subtract-at-load drains vmcnt early, kills prefetch.
// Round 19: keep sincosf -- its long ALU preamble staggers the waves' load
// bursts; __sinf/__cosf was a reproducible +5.4us regression despite lower
// VALUBusy. Issue-time distribution beats instruction count when latency-bound.)

#define BFLY(ar, ai, br, bi, wc, wsn)    \
    do {                                 \
        const float dr_ = (ar) - (br);   \
        const float di_ = (ai) - (bi);   \
        (ar) += (br);                    \
        (ai) += (bi);                    \
        (br) = dr_ * (wc)-di_ * (wsn);   \
        (bi) = dr_ * (wsn) + di_ * (wc); \
    } while (0)

#define XSTAGE(vr, vi, XF, cc, ss, sg)                    \
    do {                                                  \
        _Pragma("unroll") for (int j = 0; j < 8; ++j) {   \
            const float pr_ = XF(vr[j]), pi_ = XF(vi[j]); \
            const float xr_ = fmaf((sg), vr[j], pr_);     \
            const float xi_ = fmaf((sg), vi[j], pi_);     \
            vr[j] = xr_ * (cc)-xi_ * (ss);                \
            vi[j] = xr_ * (ss) + xi_ * (cc);              \
        }                                                 \
    } while (0)

#define FFT128(vr, vi)                                                \
    do {                                                              \
        _Pragma("unroll") for (int j = 0; j < 4; ++j)                 \
            BFLY(vr[j], vi[j], vr[j + 4], vi[j + 4], c64[j], s64[j]); \
        BFLY(vr[0], vi[0], vr[2], vi[2], c32[0], s32[0]);             \
        BFLY(vr[1], vi[1], vr[3], vi[3], c32[1], s32[1]);             \
        BFLY(vr[4], vi[4], vr[6], vi[6], c32[0], s32[0]);             \
        BFLY(vr[5], vi[5], vr[7], vi[7], c32[1], s32[1]);             \
        _Pragma("unroll") for (int j = 0; j < 8; j += 2)              \
            BFLY(vr[j], vi[j], vr[j + 1], vi[j + 1], c16v, s16v);     \
        XSTAGE(vr, vi, x8f, c8v, s8v, sg8);                           \
        XSTAGE(vr, vi, x4f, c4v, s4v, sg4);                           \
        XSTAGE(vr, vi, x2f, c2v, s2v, sg2);                           \
        _Pragma("unroll") for (int j = 0; j < 8; ++j) {               \
            const float pr_ = x1f(vr[j]), pi_ = x1f(vi[j]);           \
            vr[j] = fmaf(sg1, vr[j], pr_);                            \
            vi[j] = fmaf(sg1, vi[j], pi_);                            \
        }                                                             \
    } while (0)

// RAW loads only -- waitcnt defers to STROW, so these fly under the col pass
#define LDROW(ch, buf)                                                                  \
    do {                                                                                \
        const float* pe_ = pred + ibase + (size_t)(ch)*NPIX + (size_t)(2 * rrow) * IMG; \
        const float* ge_ = gt + ibase + (size_t)(ch)*NPIX + (size_t)(2 * rrow) * IMG;   \
        _Pragma("unroll") for (int j = 0; j < 8; ++j) {                                 \
            const int o_ = 16 * j + l;                                                  \
            buf[j] = pe_[o_];                                                           \
            buf[8 + j] = pe_[IMG + o_];                                                 \
            buf[16 + j] = ge_[o_];                                                      \
            buf[24 + j] = ge_[IMG + o_];                                                \
        }                                                                               \
    } while (0)

#define STROW(buf, zb)                                            \
    do {                                                          \
        _Pragma("unroll") for (int j = 0; j < 8; ++j) {           \
            vr[j] = 0.5f * (buf[j] - buf[16 + j]);                \
            vi[j] = 0.5f * (buf[8 + j] - buf[24 + j]);            \
        }                                                         \
        FFT128(vr, vi);                                           \
        _Pragma("unroll") for (int j = 0; j < 8; ++j)             \
            (zb)[rrow * LSU + 16 * j + l] = packh2(vr[j], vi[j]); \
    } while (0)

#define COLONE(u, wf, zb)                                          \
    do {                                                           \
        const int c1_ = rev7(u);                                   \
        const int c2_ = rev7((128 - (u)) & 127);                   \
        _Pragma("unroll") for (int j = 0; j < 8; ++j) {            \
            const int rowo_ = (8 * j + zr) * LSU;                  \
            const float2 A_ = unpackh2((zb)[rowo_ + c1_]);         \
            const float2 B_ = unpackh2((zb)[rowo_ + c2_]);         \
            vr[j] = odd ? (A_.y + B_.y) : (A_.x + B_.x);           \
            vi[j] = odd ? (B_.x - A_.x) : (A_.y - B_.y);           \
        }                                                          \
        FFT128(vr, vi);                                            \
        const float u2f_ = (float)((u) * (u));                     \
        _Pragma("unroll") for (int j = 0; j < 8; ++j) {            \
            const float r2f_ = dy2f[j] + u2f_;                     \
            if ((wf) != 0.0f && r2f_ <= 8100.0f) {                 \
                const int rc_ = (int)ceilf(sqrtf(r2f_) - 3e-4f);   \
                atomicAdd(&s_h[wave][s_rc2bin[rc_]],               \
                          (wf) * (vr[j] * vr[j] + vi[j] * vi[j])); \
            }                                                      \
        }                                                          \
    } while (0)

#define COLPHASE(ch, zb)                                              \
    do {                                                              \
        COLONE(u0, (u0 == 0) ? 1.0f : 2.0f, zb);                      \
        if (wave == (ch)) { COLONE(64, (g == 0) ? 1.0f : 0.0f, zb); } \
    } while (0)

// One block (16 waves) per batch element, channel-pipelined: channel k+1's
// global loads fly under channel k's column pass. Each 16-lane group owns one
// 128-pt FFT (8 complex/lane, slots 16j+l); stages m=64/32/16 lane-local,
// m=8/4/2/1 via DPP. Row-pair Hermitian packing; fp16x2 Z double-buffer.
__global__ __launch_bounds__(1024, 4) void fused_psnr_kernel(const float* __restrict__ pred,
                                                             const float* __restrict__ gt,
                                                             float* __restrict__ out) {
    __shared__ unsigned s_z[2][ZN];  // 2 x 33 KiB fp16x2 Z double-buffer
    __shared__ float s_h[16][66];    // per-wave hist, padded stride
    __shared__ int s_rc2bin[91];

    const int tid = threadIdx.x;
    const int lane = tid & 63;
    const int wave = tid >> 6;  // 0..15
    const int l = lane & 15;    // position within 16-lane FFT group
    const int g = lane >> 4;    // group 0..3 within wave
    const int b = blockIdx.x;

    for (int i = tid; i < 16 * 66; i += 1024) (&s_h[0][0])[i] = 0.0f;
    if (tid < 91) {
        int t = 0;
        while (t < 63 && c_thr[t] < tid) ++t;  // smallest t with thr[t] >= radius
        s_rc2bin[tid] = t;
    }

    // ---- register-resident twiddles (W = exp(-2*pi*i/128)); sincosf on
    // purpose -- see header note on wave staggering ----
    const float K = -6.2831853071795864769f * (1.0f / 128.0f);
    float c64[4], s64[4], c32[2], s32[2], c16v, s16v;
#pragma unroll
    for (int j = 0; j < 4; ++j) sincosf(K * (float)(16 * j + l), &s64[j], &c64[j]);
    sincosf(K * (float)(2 * l), &s32[0], &c32[0]);
    sincosf(K * (float)(2 * l + 32), &s32[1], &c32[1]);
    sincosf(K * (float)(4 * l), &s16v, &c16v);
    float c8v, s8v, c4v, s4v, c2v, s2v;
    sincosf(K * (float)((l & 8) ? (l & 7) * 8 : 0), &s8v, &c8v);
    sincosf(K * (float)((l & 4) ? (l & 3) * 16 : 0), &s4v, &c4v);
    sincosf(K * (float)((l & 2) ? (l & 1) * 32 : 0), &s2v, &c2v);
    const float sg8 = (l & 8) ? -1.0f : 1.0f;
    const float sg4 = (l & 4) ? -1.0f : 1.0f;
    const float sg2 = (l & 2) ? -1.0f : 1.0f;
    const float sg1 = (l & 1) ? -1.0f : 1.0f;

    const size_t ibase = (size_t)b * 3 * NPIX;
    const int rrow = (wave & 7) + 32 * (wave >> 3) + 8 * g;  // 0..63, unique per unit
    const int u0 = (wave & 3) + ((wave >> 2) << 4) + 4 * g;  // 0..63, unique per unit
    const int zr = l >> 1;
    const int odd = l & 1;

    // per-(lane,j) row-frequency distance^2: slot p=16j+l holds freq rev7(p)
    float dy2f[8];
    const int r4 = ((l & 1) << 3) | ((l & 2) << 1) | ((l & 4) >> 1) | ((l & 8) >> 3);
#pragma unroll
    for (int j = 0; j < 8; ++j) {
        const int fy = (((j & 1) << 2) | (j & 2) | ((j & 4) >> 2)) | (r4 << 3);
        const int dy = (fy < 64) ? fy : 128 - fy;
        dy2f[j] = (float)(dy * dy);
    }

    float bufA[32], bufB[32], vr[8], vi[8];

    // ---- channel pipeline ----
    LDROW(0, bufA);
    STROW(bufA, s_z[0]);
    __syncthreads();  // z0 ready (also covers s_h/rc2bin init)

    LDROW(1, bufB);   // ch1 loads fly under ch0 col pass
    COLPHASE(0, s_z[0]);
    STROW(bufB, s_z[1]);
    __syncthreads();  // z1 ready; z0 readers done

    LDROW(2, bufA);   // ch2 loads fly under ch1 col pass
    COLPHASE(1, s_z[1]);
    STROW(bufA, s_z[0]);
    __syncthreads();  // z0 ready; z1 readers done

    COLPHASE(2, s_z[0]);
    __syncthreads();  // all hist contributions visible

    // ---- combine 16 wave-hists, inclusive prefix, PSNR (wave 0 only) ----
    if (tid < 64) {
        float tot = 0.0f;
#pragma unroll
        for (int w = 0; w < 16; ++w) tot += s_h[w][tid];
        s_h[0][tid] = tot;
        float cum = 0.0f;
        for (int j = 0; j <= tid; ++j) cum += s_h[0][j];
        out[b * NT + tid] = 84.2883987849f - 10.0f * log10f(cum);  // 20*log10(16384) - 10*log10(cum)
    }
}

extern "C" void kernel_launch(void* const* d_in, const int* in_sizes, int n_in,
                              void* d_out, int out_size, void* d_ws, size_t ws_size,
                              hipStream_t stream) {
    const float* pred = (const float*)d_in[0];
    const float* gt = (const float*)d_in[1];
    float* out = (float*)d_out;
    fused_psnr_kernel<<<256, 1024, 0, stream>>>(pred, gt, out);
}